// Round 5
// baseline (880.263 us; speedup 1.0000x reference)
//
#include <hip/hip_runtime.h>

// LIF forward: x[T,B,D] fp32 -> spikes[T,B,D] fp32.
// TAU=1, THRESH=1, GAMA=1 (gama only affects backward; forward is Heaviside).
// Recurrence per (b,d) lane: mem = mem + x[t]; s = (mem>=1)?1:0; mem *= (1-s).
// Memory-bound: 1 GiB traffic, ~170us floor at 6.3 TB/s.

#define LIF_THRESH 1.0f
#define LIF_TAU    1.0f

__global__ __launch_bounds__(256) void lif_fwd_kernel(
    const float4* __restrict__ x,   // [T][n_per_t] as float4
    float4* __restrict__ out,       // [T][n_per_t] as float4
    int n_per_t,                    // B*D/4 float4 elements per timestep
    int T)
{
    int i = blockIdx.x * blockDim.x + threadIdx.x;
    if (i >= n_per_t) return;

    const float4* xp = x + i;
    float4* op = out + i;

    float mx = 0.f, my = 0.f, mz = 0.f, mw = 0.f;

    #pragma unroll 8
    for (int t = 0; t < T; ++t) {
        float4 xt = xp[(size_t)t * n_per_t];

        mx = LIF_TAU * mx + xt.x;
        my = LIF_TAU * my + xt.y;
        mz = LIF_TAU * mz + xt.z;
        mw = LIF_TAU * mw + xt.w;

        float sx = (mx >= LIF_THRESH) ? LIF_THRESH : 0.f;
        float sy = (my >= LIF_THRESH) ? LIF_THRESH : 0.f;
        float sz = (mz >= LIF_THRESH) ? LIF_THRESH : 0.f;
        float sw = (mw >= LIF_THRESH) ? LIF_THRESH : 0.f;

        // hard reset scaled by spike: mem *= (1 - spike)
        mx *= (1.f - sx);
        my *= (1.f - sy);
        mz *= (1.f - sz);
        mw *= (1.f - sw);

        op[(size_t)t * n_per_t] = make_float4(sx, sy, sz, sw);
    }
}

extern "C" void kernel_launch(void* const* d_in, const int* in_sizes, int n_in,
                              void* d_out, int out_size, void* d_ws, size_t ws_size,
                              hipStream_t stream) {
    const int T = 64;                       // x is [64, 128, 16384]
    const float4* x = (const float4*)d_in[0];
    float4* out = (float4*)d_out;

    int n_total  = in_sizes[0];             // T*B*D
    int n_per_t  = (n_total / T) / 4;       // float4 per timestep = 524288

    int block = 256;
    int grid  = (n_per_t + block - 1) / block;  // 2048 blocks

    lif_fwd_kernel<<<grid, block, 0, stream>>>(x, out, n_per_t, T);
}